// Round 4
// baseline (2652.030 us; speedup 1.0000x reference)
//
#include <hip/hip_runtime.h>

#define NEG_SLOPE 0.1f

static inline int cdiv(int a, int b) { return (a + b - 1) / b; }

// ---------------- round-0 monolithic blocked conv + leaky relu (L2..L10) ----------------
// Measured-good for CIN>=32 layers (VGPR=72, no spills). BODY MUST NOT CHANGE without
// per-layer counters. Batch count is implied by gridDim.z = NB * (COUT/TCO); the b-decode
// below works for any NB, so batching both images needs no code change here.
template <int K, int S, int PAD, int CIN, int COUT,
          int HIN, int WIN, int HOUT, int WOUT, int TCO, int TW>
__global__ __launch_bounds__(256) void conv_blk(const float* __restrict__ x,
                                                const float* __restrict__ w,
                                                const float* __restrict__ bs,
                                                float* __restrict__ y) {
    constexpr int SLOTS_W = WOUT / TW;      // thread-slots per output row
    constexpr int NSLOT   = HOUT * SLOTS_W; // thread-slots per (b, co_group) plane
    constexpr int NW      = TCO * CIN * K * K;

    __shared__ float wlds[NW];

    const int zz  = blockIdx.z;
    const int b   = zz / (COUT / TCO);
    const int cob = (zz % (COUT / TCO)) * TCO;

    // stage weights: wlds[((ci*K+kh)*K+kw)*TCO + t] = w[(cob+t)][ci][kh][kw]
    for (int i = threadIdx.x; i < NW; i += 256) {
        int t    = i % TCO;
        int rest = i / TCO;                 // = ci*K*K + kh*K + kw
        wlds[i] = w[(size_t)(cob + t) * (CIN * K * K) + rest];
    }
    __syncthreads();

    const int slot = blockIdx.x * 256 + threadIdx.x;
    if (slot >= NSLOT) return;

    const int ho = slot / SLOTS_W;
    const int wo = (slot % SLOTS_W) * TW;

    const float* xb = x + (size_t)b * CIN * HIN * WIN;

    float acc[TCO][TW];
#pragma unroll
    for (int t = 0; t < TCO; ++t) {
        float bv = bs[cob + t];
#pragma unroll
        for (int j = 0; j < TW; ++j) acc[t][j] = bv;
    }

    const int hi0 = ho * S - PAD;
    const int wi0 = wo * S - PAD;
    constexpr int L = (TW - 1) * S + K;     // input columns needed per row
    const bool interior = (hi0 >= 0) && (hi0 + K <= HIN) && (wi0 >= 0) && (wi0 + L <= WIN);

    for (int ci = 0; ci < CIN; ++ci) {
        const float* xc = xb + (size_t)ci * HIN * WIN;
        const float* wc = &wlds[(ci * K * K) * TCO];
#pragma unroll
        for (int kh = 0; kh < K; ++kh) {
            const int hi = hi0 + kh;
            float r[L];
            if (interior) {
                const float* xr = xc + (size_t)hi * WIN + wi0;
#pragma unroll
                for (int u = 0; u < L; ++u) r[u] = xr[u];
            } else {
                const bool rowok = (unsigned)hi < (unsigned)HIN;
#pragma unroll
                for (int u = 0; u < L; ++u) {
                    const int wi = wi0 + u;
                    r[u] = (rowok && (unsigned)wi < (unsigned)WIN)
                               ? xc[(size_t)hi * WIN + wi] : 0.0f;
                }
            }
#pragma unroll
            for (int kw = 0; kw < K; ++kw) {
                const float* wg = wc + (kh * K + kw) * TCO;
                float w8[TCO];
#pragma unroll
                for (int t = 0; t < TCO; ++t) w8[t] = wg[t];
#pragma unroll
                for (int j = 0; j < TW; ++j) {
                    const float xv = r[kw + j * S];
#pragma unroll
                    for (int t = 0; t < TCO; ++t)
                        acc[t][j] = fmaf(xv, w8[t], acc[t][j]);
                }
            }
        }
    }

    // epilogue: leaky relu + store
#pragma unroll
    for (int t = 0; t < TCO; ++t) {
        float* yr = y + (((size_t)b * COUT + cob + t) * HOUT + ho) * WOUT + wo;
#pragma unroll
        for (int j = 0; j < TW; ++j) {
            const float v = acc[t][j];
            yr[j] = v >= 0.0f ? v : NEG_SLOPE * v;
        }
    }
}

// Compile-time geometry: interior rectangle (no bounds checks needed) vs edge ring.
template <int K, int S, int PAD, int HIN, int WIN, int HOUT, int WOUT, int TW>
struct Geom {
    static constexpr int SLOTS_W = WOUT / TW;       // thread-slots per output row
    static constexpr int NSLOT   = HOUT * SLOTS_W;  // slots per (b, co_group) plane
    static constexpr int L       = (TW - 1) * S + K;
    static constexpr int HO_LO   = (PAD + S - 1) / S;
    static constexpr int HO_HI0  = (HIN - K + PAD) / S + 1;
    static constexpr int HO_HI   = HO_HI0 < HOUT ? HO_HI0 : HOUT;
    static constexpr int WS_LO   = (PAD + TW * S - 1) / (TW * S);
    static constexpr int WS_HI0  = (WIN + PAD - L) / (TW * S) + 1;
    static constexpr int WS_HI   = WS_HI0 < SLOTS_W ? WS_HI0 : SLOTS_W;
    static constexpr int WS_N    = WS_HI - WS_LO;
    static constexpr int N_INT   = (HO_HI - HO_LO) * WS_N;
    static constexpr int N_EDGE  = NSLOT - N_INT;
};

// ---------------- interior conv + leaky relu, L1 only (measured 144us @ NB=4) ----------
// NB=8 batches both images in one dispatch: x1 holds batches [0,NB/2), x2 the rest.
template <int K, int S, int PAD, int CIN, int COUT,
          int HIN, int WIN, int HOUT, int WOUT, int TCO, int TW, int NB>
__global__ __launch_bounds__(256, 4) void conv_int(const float* __restrict__ x1,
                                                   const float* __restrict__ x2,
                                                   const float* __restrict__ w,
                                                   const float* __restrict__ bs,
                                                   float* __restrict__ y) {
    using G = Geom<K, S, PAD, HIN, WIN, HOUT, WOUT, TW>;
    constexpr int NW = TCO * CIN * K * K;

    __shared__ float wlds[NW];

    const int zz  = blockIdx.z;
    const int b   = zz / (COUT / TCO);
    const int cob = (zz % (COUT / TCO)) * TCO;

    for (int i = threadIdx.x; i < NW; i += 256) {
        int t    = i % TCO;
        int rest = i / TCO;
        wlds[i] = w[(size_t)(cob + t) * (CIN * K * K) + rest];
    }
    __syncthreads();

    const int s = blockIdx.x * 256 + threadIdx.x;
    if (s >= G::N_INT) return;

    const int ho = G::HO_LO + s / G::WS_N;
    const int wo = (G::WS_LO + s % G::WS_N) * TW;

    const float* xim = x1;
    int bb = b;
    if constexpr (NB == 8) {
        if (b >= 4) { xim = x2; bb = b - 4; }
    }
    const float* xb = xim + (size_t)bb * CIN * HIN * WIN;

    float acc[TCO][TW];
#pragma unroll
    for (int t = 0; t < TCO; ++t) {
        float bv = bs[cob + t];
#pragma unroll
        for (int j = 0; j < TW; ++j) acc[t][j] = bv;
    }

    const int hi0 = ho * S - PAD;
    const int wi0 = wo * S - PAD;

#pragma unroll
    for (int ci = 0; ci < CIN; ++ci) {
        const float* xc = xb + (size_t)ci * HIN * WIN;
        const float* wc = &wlds[(ci * K * K) * TCO];
#pragma unroll
        for (int kh = 0; kh < K; ++kh) {
            const float* xr = xc + (size_t)(hi0 + kh) * WIN + wi0;
            float r[G::L];
#pragma unroll
            for (int u = 0; u < G::L; ++u) r[u] = xr[u];
#pragma unroll
            for (int kw = 0; kw < K; ++kw) {
                const float* wg = wc + (kh * K + kw) * TCO;
                float w8[TCO];
                if constexpr ((TCO % 4) == 0) {
#pragma unroll
                    for (int t = 0; t < TCO; t += 4) {
                        float4 q = *reinterpret_cast<const float4*>(wg + t);
                        w8[t] = q.x; w8[t + 1] = q.y; w8[t + 2] = q.z; w8[t + 3] = q.w;
                    }
                } else {
#pragma unroll
                    for (int t = 0; t < TCO; ++t) w8[t] = wg[t];
                }
#pragma unroll
                for (int j = 0; j < TW; ++j) {
                    const float xv = r[kw + j * S];
#pragma unroll
                    for (int t = 0; t < TCO; ++t)
                        acc[t][j] = fmaf(xv, w8[t], acc[t][j]);
                }
            }
        }
    }

#pragma unroll
    for (int t = 0; t < TCO; ++t) {
        float* yr = y + (((size_t)b * COUT + cob + t) * HOUT + ho) * WOUT + wo;
        float v[TW];
#pragma unroll
        for (int j = 0; j < TW; ++j) {
            const float a = acc[t][j];
            v[j] = a >= 0.0f ? a : NEG_SLOPE * a;
        }
        if constexpr (TW == 4) {
            *reinterpret_cast<float4*>(yr) = make_float4(v[0], v[1], v[2], v[3]);
        } else if constexpr (TW == 2) {
            *reinterpret_cast<float2*>(yr) = make_float2(v[0], v[1]);
        } else {
#pragma unroll
            for (int j = 0; j < TW; ++j) yr[j] = v[j];
        }
    }
}

// ---------------- edge conv + leaky relu, L1 only ----------------
template <int K, int S, int PAD, int CIN, int COUT,
          int HIN, int WIN, int HOUT, int WOUT, int TCO, int TW, int NB>
__global__ __launch_bounds__(256) void conv_edge(const float* __restrict__ x1,
                                                 const float* __restrict__ x2,
                                                 const float* __restrict__ w,
                                                 const float* __restrict__ bs,
                                                 float* __restrict__ y) {
    using G = Geom<K, S, PAD, HIN, WIN, HOUT, WOUT, TW>;
    constexpr int SLOTS_W = G::SLOTS_W;
    constexpr int NW = TCO * CIN * K * K;

    __shared__ float wlds[NW];

    const int zz  = blockIdx.z;
    const int b   = zz / (COUT / TCO);
    const int cob = (zz % (COUT / TCO)) * TCO;

    for (int i = threadIdx.x; i < NW; i += 256) {
        int t    = i % TCO;
        int rest = i / TCO;
        wlds[i] = w[(size_t)(cob + t) * (CIN * K * K) + rest];
    }
    __syncthreads();

    const int s = blockIdx.x * 256 + threadIdx.x;
    if (s >= G::N_EDGE) return;

    constexpr int TOPN = G::HO_LO * SLOTS_W;
    constexpr int BOTN = (HOUT - G::HO_HI) * SLOTS_W;
    constexpr int MIDH = G::HO_HI - G::HO_LO;
    constexpr int LW   = G::WS_LO;
    constexpr int RW   = SLOTS_W - G::WS_HI;
    constexpr int LN   = MIDH * LW;

    int ho = 0, ws = 0;
    if (s < TOPN) {
        ho = s / SLOTS_W;
        ws = s % SLOTS_W;
    } else if (s < TOPN + BOTN) {
        int t = s - TOPN;
        ho = G::HO_HI + t / SLOTS_W;
        ws = t % SLOTS_W;
    } else if (s < TOPN + BOTN + LN) {
        int t = s - TOPN - BOTN;
        constexpr int D = LW > 0 ? LW : 1;
        ho = G::HO_LO + t / D;
        ws = t % D;
    } else {
        int t = s - TOPN - BOTN - LN;
        constexpr int D = RW > 0 ? RW : 1;
        ho = G::HO_LO + t / D;
        ws = G::WS_HI + t % D;
    }
    const int wo = ws * TW;

    const float* xim = x1;
    int bb = b;
    if constexpr (NB == 8) {
        if (b >= 4) { xim = x2; bb = b - 4; }
    }
    const float* xb = xim + (size_t)bb * CIN * HIN * WIN;

    float acc[TCO][TW];
#pragma unroll
    for (int t = 0; t < TCO; ++t) {
        float bv = bs[cob + t];
#pragma unroll
        for (int j = 0; j < TW; ++j) acc[t][j] = bv;
    }

    const int hi0 = ho * S - PAD;
    const int wi0 = wo * S - PAD;

#pragma unroll 2
    for (int ci = 0; ci < CIN; ++ci) {
        const float* xc = xb + (size_t)ci * HIN * WIN;
        const float* wc = &wlds[(ci * K * K) * TCO];
#pragma unroll
        for (int kh = 0; kh < K; ++kh) {
            const int hi = hi0 + kh;
            const bool rowok = (unsigned)hi < (unsigned)HIN;
            const float* xr = xc + (size_t)(rowok ? hi : 0) * WIN;
            float r[G::L];
#pragma unroll
            for (int u = 0; u < G::L; ++u) {
                const int wi = wi0 + u;
                const bool ok = rowok && (unsigned)wi < (unsigned)WIN;
                const float v = xr[ok ? wi : 0];
                r[u] = ok ? v : 0.0f;
            }
#pragma unroll
            for (int kw = 0; kw < K; ++kw) {
                const float* wg = wc + (kh * K + kw) * TCO;
                float w8[TCO];
#pragma unroll
                for (int t = 0; t < TCO; ++t) w8[t] = wg[t];
#pragma unroll
                for (int j = 0; j < TW; ++j) {
                    const float xv = r[kw + j * S];
#pragma unroll
                    for (int t = 0; t < TCO; ++t)
                        acc[t][j] = fmaf(xv, w8[t], acc[t][j]);
                }
            }
        }
    }

#pragma unroll
    for (int t = 0; t < TCO; ++t) {
        float* yr = y + (((size_t)b * COUT + cob + t) * HOUT + ho) * WOUT + wo;
#pragma unroll
        for (int j = 0; j < TW; ++j) {
            const float v = acc[t][j];
            yr[j] = v >= 0.0f ? v : NEG_SLOPE * v;
        }
    }
}

// ---------------- bilinear warp (B=4, H=12, W=24) ----------------
__global__ void warp_kernel(const float* __restrict__ img, const float* __restrict__ flow,
                            float* __restrict__ out, int C) {
    const int H = 12, W = 24, HW = 288;
    int idx = blockIdx.x * blockDim.x + threadIdx.x;
    int total = 4 * C * HW;
    if (idx >= total) return;
    int w = idx % W;
    int h = (idx / W) % H;
    int c = (idx / HW) % C;
    int b = idx / (HW * C);

    float fx = flow[(((size_t)b * 2 + 0) * H + h) * W + w] * 0.625f;
    float fy = flow[(((size_t)b * 2 + 1) * H + h) * W + w] * 0.625f;
    float px = (float)w + fx;
    float py = (float)h + fy;
    float x0f = floorf(px);
    float y0f = floorf(py);
    float wx = px - x0f;
    float wy = py - y0f;
    int x0 = (int)x0f;
    int y0 = (int)y0f;

    const float* ip = img + ((size_t)b * C + c) * HW;
    auto g = [&](int yi, int xi) -> float {
        if (xi < 0 || xi > W - 1 || yi < 0 || yi > H - 1) return 0.0f;
        return ip[yi * W + xi];
    };
    float v = g(y0, x0) * (1.0f - wx) * (1.0f - wy)
            + g(y0, x0 + 1) * wx * (1.0f - wy)
            + g(y0 + 1, x0) * (1.0f - wx) * wy
            + g(y0 + 1, x0 + 1) * wx * wy;
    out[idx] = v;
}

// ---------------- correlation (7x7 disp) + lrelu ----------------
__global__ void corr_lrelu(const float* __restrict__ f1, const float* __restrict__ wp,
                           float* __restrict__ out, int C) {
    const int H = 12, W = 24, HW = 288;
    int idx = blockIdx.x * blockDim.x + threadIdx.x;
    int total = 4 * 49 * HW;
    if (idx >= total) return;
    int w = idx % W;
    int h = (idx / W) % H;
    int d = (idx / HW) % 49;
    int b = idx / (49 * HW);
    int di = d / 7 - 3;
    int dj = d % 7 - 3;
    int h2 = h + di;
    int w2 = w + dj;

    float s = 0.0f;
    if (h2 >= 0 && h2 < H && w2 >= 0 && w2 < W) {
        const float* a = f1 + (size_t)b * C * HW + h * W + w;
        const float* p = wp + (size_t)b * C * HW + h2 * W + w2;
        for (int c = 0; c < C; ++c) s = fmaf(a[(size_t)c * HW], p[(size_t)c * HW], s);
    }
    s /= (float)C;
    s = (s >= 0.0f) ? s : NEG_SLOPE * s;
    out[idx] = s;
}

// ---------------- host ----------------
extern "C" void kernel_launch(void* const* d_in, const int* in_sizes, int n_in,
                              void* d_out, int out_size, void* d_ws, size_t ws_size,
                              hipStream_t stream) {
    const float* img1 = (const float*)d_in[0];
    const float* img2 = (const float*)d_in[1];
    const float* flow = (const float*)d_in[2];
    float* out = (float*)d_out;

    const float* W[10];
    const float* Bs[10];
    for (int l = 0; l < 10; ++l) {
        W[l]  = (const float*)d_in[3 + 2 * l];
        Bs[l] = (const float*)d_in[4 + 2 * l];
    }

    float* ws = (float*)d_ws;
    using G1 = Geom<7,1,3, 384,768, 384,768, 4>;

    // Tiered workspace plans (bytes):
    //  full  (merge both images from L1): A8=75,497,472 + B8=18,874,368 + C8=18,874,368
    //                                     + F12=442,368 + WRP=221,184  -> 455.6 MB
    //  mid   (merge from L3):             A =37,748,736 + B8 + C8 + F12 + WRP -> 304.6 MB
    //  fallback (round-3 exact):          191.4 MB
    const size_t FULL_FLOATS = 75497472ull + 18874368ull + 18874368ull + 442368ull + 221184ull;
    const size_t MID_FLOATS  = 37748736ull + 18874368ull + 18874368ull + 442368ull + 221184ull;

    if (ws_size >= FULL_FLOATS * 4) {
        // ---------- full merge: batch-8 everywhere ----------
        float* A8  = ws;
        float* B8  = A8 + 75497472;
        float* C8  = B8 + 18874368;
        float* F12 = C8 + 18874368;
        float* WRP = F12 + 442368;

        conv_int<7,1,3,  3, 32, 384,768, 384,768, 8,4, 8>
            <<<dim3(cdiv(G1::N_INT, 256), 1, 8*(32/8)), 256, 0, stream>>>(img1, img2, W[0], Bs[0], A8);
        conv_edge<7,1,3,  3, 32, 384,768, 384,768, 8,4, 8>
            <<<dim3(cdiv(G1::N_EDGE, 256), 1, 8*(32/8)), 256, 0, stream>>>(img1, img2, W[0], Bs[0], A8);

        conv_blk<3,2,1, 32, 32, 384,768, 192,384, 8,4>
            <<<dim3(cdiv(192*(384/4),256),1,8*(32/8)), 256, 0, stream>>>(A8, W[1], Bs[1], B8);
        conv_blk<3,1,1, 32, 32, 192,384, 192,384, 8,4>
            <<<dim3(cdiv(192*(384/4),256),1,8*(32/8)), 256, 0, stream>>>(B8, W[2], Bs[2], C8);
        conv_blk<3,1,1, 32, 32, 192,384, 192,384, 8,4>
            <<<dim3(cdiv(192*(384/4),256),1,8*(32/8)), 256, 0, stream>>>(C8, W[3], Bs[3], A8);
        conv_blk<3,2,1, 32, 64, 192,384,  96,192, 8,4>
            <<<dim3(cdiv(96*(192/4),256),1,8*(64/8)), 256, 0, stream>>>(A8, W[4], Bs[4], B8);
        conv_blk<3,1,1, 64, 64,  96,192,  96,192, 8,4>
            <<<dim3(cdiv(96*(192/4),256),1,8*(64/8)), 256, 0, stream>>>(B8, W[5], Bs[5], C8);
        conv_blk<3,2,1, 64, 96,  96,192,  48, 96, 8,4>
            <<<dim3(cdiv(48*(96/4),256),1,8*(96/8)), 256, 0, stream>>>(C8, W[6], Bs[6], B8);
        conv_blk<3,1,1, 96, 96,  48, 96,  48, 96, 8,4>
            <<<dim3(cdiv(48*(96/4),256),1,8*(96/8)), 256, 0, stream>>>(B8, W[7], Bs[7], C8);
        conv_blk<3,2,1, 96,128,  48, 96,  24, 48, 8,4>
            <<<dim3(cdiv(24*(48/4),256),1,8*(128/8)), 256, 0, stream>>>(C8, W[8], Bs[8], B8);
        conv_blk<3,2,1,128,192,  24, 48,  12, 24, 8,4>
            <<<dim3(cdiv(12*(24/4),256),1,8*(192/8)), 256, 0, stream>>>(B8, W[9], Bs[9], F12);

        float* f1 = F12;
        float* f2 = F12 + 221184;  // batches 4..7 = img2 features
        warp_kernel<<<cdiv(4 * 192 * 288, 256), 256, 0, stream>>>(f2, flow, WRP, 192);
        corr_lrelu<<<cdiv(4 * 49 * 288, 256), 256, 0, stream>>>(f1, WRP, out, 192);

    } else if (ws_size >= MID_FLOATS * 4) {
        // ---------- mid merge: L1/L2 per-image, L3.. batch-8 ----------
        float* A   = ws;                     // 37,748,736: per-image L1 out; later L4 out (batch-8)
        float* B8  = A + 37748736;           // 18,874,368
        float* C8  = B8 + 18874368;          // 18,874,368
        float* F12 = C8 + 18874368;
        float* WRP = F12 + 442368;

        for (int i = 0; i < 2; ++i) {
            const float* img = (i == 0) ? img1 : img2;
            float* l2out = B8 + (size_t)i * 9437184;  // half of batch-8 L2 buffer
            conv_int<7,1,3,  3, 32, 384,768, 384,768, 8,4, 4>
                <<<dim3(cdiv(G1::N_INT, 256), 1, 4*(32/8)), 256, 0, stream>>>(img, img, W[0], Bs[0], A);
            conv_edge<7,1,3,  3, 32, 384,768, 384,768, 8,4, 4>
                <<<dim3(cdiv(G1::N_EDGE, 256), 1, 4*(32/8)), 256, 0, stream>>>(img, img, W[0], Bs[0], A);
            conv_blk<3,2,1, 32, 32, 384,768, 192,384, 8,4>
                <<<dim3(cdiv(192*(384/4),256),1,4*(32/8)), 256, 0, stream>>>(A, W[1], Bs[1], l2out);
        }
        conv_blk<3,1,1, 32, 32, 192,384, 192,384, 8,4>
            <<<dim3(cdiv(192*(384/4),256),1,8*(32/8)), 256, 0, stream>>>(B8, W[2], Bs[2], C8);
        conv_blk<3,1,1, 32, 32, 192,384, 192,384, 8,4>
            <<<dim3(cdiv(192*(384/4),256),1,8*(32/8)), 256, 0, stream>>>(C8, W[3], Bs[3], A);
        conv_blk<3,2,1, 32, 64, 192,384,  96,192, 8,4>
            <<<dim3(cdiv(96*(192/4),256),1,8*(64/8)), 256, 0, stream>>>(A, W[4], Bs[4], B8);
        conv_blk<3,1,1, 64, 64,  96,192,  96,192, 8,4>
            <<<dim3(cdiv(96*(192/4),256),1,8*(64/8)), 256, 0, stream>>>(B8, W[5], Bs[5], C8);
        conv_blk<3,2,1, 64, 96,  96,192,  48, 96, 8,4>
            <<<dim3(cdiv(48*(96/4),256),1,8*(96/8)), 256, 0, stream>>>(C8, W[6], Bs[6], B8);
        conv_blk<3,1,1, 96, 96,  48, 96,  48, 96, 8,4>
            <<<dim3(cdiv(48*(96/4),256),1,8*(96/8)), 256, 0, stream>>>(B8, W[7], Bs[7], C8);
        conv_blk<3,2,1, 96,128,  48, 96,  24, 48, 8,4>
            <<<dim3(cdiv(24*(48/4),256),1,8*(128/8)), 256, 0, stream>>>(C8, W[8], Bs[8], B8);
        conv_blk<3,2,1,128,192,  24, 48,  12, 24, 8,4>
            <<<dim3(cdiv(12*(24/4),256),1,8*(192/8)), 256, 0, stream>>>(B8, W[9], Bs[9], F12);

        float* f1 = F12;
        float* f2 = F12 + 221184;
        warp_kernel<<<cdiv(4 * 192 * 288, 256), 256, 0, stream>>>(f2, flow, WRP, 192);
        corr_lrelu<<<cdiv(4 * 49 * 288, 256), 256, 0, stream>>>(f1, WRP, out, 192);

    } else {
        // ---------- fallback: round-3 exact (measured 2515 us) ----------
        size_t off = 0;
        float* bufA = ws + off; off += 37748736;  // 4*32*384*768
        float* bufB = ws + off; off += 9437184;   // 4*32*192*384
        float* f1   = ws + off; off += 221184;    // 4*192*12*24
        float* f2   = ws + off; off += 221184;
        float* wrp  = ws + off; off += 221184;

        auto chain = [&](const float* img, float* fout) {
            conv_int<7,1,3,  3, 32, 384,768, 384,768, 8,4, 4>
                <<<dim3(cdiv(G1::N_INT, 256), 1, 4*(32/8)), 256, 0, stream>>>(img, img, W[0], Bs[0], bufA);
            conv_edge<7,1,3,  3, 32, 384,768, 384,768, 8,4, 4>
                <<<dim3(cdiv(G1::N_EDGE, 256), 1, 4*(32/8)), 256, 0, stream>>>(img, img, W[0], Bs[0], bufA);
            conv_blk<3,2,1, 32, 32, 384,768, 192,384, 8,4>
                <<<dim3(cdiv(192*(384/4),256),1,4*(32/8)), 256, 0, stream>>>(bufA, W[1], Bs[1], bufB);
            conv_blk<3,1,1, 32, 32, 192,384, 192,384, 8,4>
                <<<dim3(cdiv(192*(384/4),256),1,4*(32/8)), 256, 0, stream>>>(bufB, W[2], Bs[2], bufA);
            conv_blk<3,1,1, 32, 32, 192,384, 192,384, 8,4>
                <<<dim3(cdiv(192*(384/4),256),1,4*(32/8)), 256, 0, stream>>>(bufA, W[3], Bs[3], bufB);
            conv_blk<3,2,1, 32, 64, 192,384,  96,192, 8,4>
                <<<dim3(cdiv(96*(192/4),256),1,4*(64/8)), 256, 0, stream>>>(bufB, W[4], Bs[4], bufA);
            conv_blk<3,1,1, 64, 64,  96,192,  96,192, 8,4>
                <<<dim3(cdiv(96*(192/4),256),1,4*(64/8)), 256, 0, stream>>>(bufA, W[5], Bs[5], bufB);
            conv_blk<3,2,1, 64, 96,  96,192,  48, 96, 8,4>
                <<<dim3(cdiv(48*(96/4),256),1,4*(96/8)), 256, 0, stream>>>(bufB, W[6], Bs[6], bufA);
            conv_blk<3,1,1, 96, 96,  48, 96,  48, 96, 8,4>
                <<<dim3(cdiv(48*(96/4),256),1,4*(96/8)), 256, 0, stream>>>(bufA, W[7], Bs[7], bufB);
            conv_blk<3,2,1, 96,128,  48, 96,  24, 48, 8,4>
                <<<dim3(cdiv(24*(48/4),256),1,4*(128/8)), 256, 0, stream>>>(bufB, W[8], Bs[8], bufA);
            conv_blk<3,2,1,128,192,  24, 48,  12, 24, 8,4>
                <<<dim3(cdiv(12*(24/4),256),1,4*(192/8)), 256, 0, stream>>>(bufA, W[9], Bs[9], fout);
        };

        chain(img1, f1);
        chain(img2, f2);

        warp_kernel<<<cdiv(4 * 192 * 288, 256), 256, 0, stream>>>(f2, flow, wrp, 192);
        corr_lrelu<<<cdiv(4 * 49 * 288, 256), 256, 0, stream>>>(f1, wrp, out, 192);
    }
}

// Round 5
// 2087.194 us; speedup vs baseline: 1.2706x; 1.2706x over previous
//
#include <hip/hip_runtime.h>

#define NEG_SLOPE 0.1f

static inline int cdiv(int a, int b) { return (a + b - 1) / b; }

// ---------------- round-0/3 monolithic blocked conv + leaky relu (L2..L10) -------------
// Measured-good for CIN>=32 layers (VGPR=72, no spills, ~170us at batch-4 CIN=32 plane).
// BODY AND TEMPLATE ARGS MUST NOT CHANGE (rule: codegen perturbation cost 35us on conv_int
// in round 4). Batch count comes solely from gridDim.z = NB*(COUT/TCO); b-decode is generic.
template <int K, int S, int PAD, int CIN, int COUT,
          int HIN, int WIN, int HOUT, int WOUT, int TCO, int TW>
__global__ __launch_bounds__(256) void conv_blk(const float* __restrict__ x,
                                                const float* __restrict__ w,
                                                const float* __restrict__ bs,
                                                float* __restrict__ y) {
    constexpr int SLOTS_W = WOUT / TW;      // thread-slots per output row
    constexpr int NSLOT   = HOUT * SLOTS_W; // thread-slots per (b, co_group) plane
    constexpr int NW      = TCO * CIN * K * K;

    __shared__ float wlds[NW];

    const int zz  = blockIdx.z;
    const int b   = zz / (COUT / TCO);
    const int cob = (zz % (COUT / TCO)) * TCO;

    // stage weights: wlds[((ci*K+kh)*K+kw)*TCO + t] = w[(cob+t)][ci][kh][kw]
    for (int i = threadIdx.x; i < NW; i += 256) {
        int t    = i % TCO;
        int rest = i / TCO;                 // = ci*K*K + kh*K + kw
        wlds[i] = w[(size_t)(cob + t) * (CIN * K * K) + rest];
    }
    __syncthreads();

    const int slot = blockIdx.x * 256 + threadIdx.x;
    if (slot >= NSLOT) return;

    const int ho = slot / SLOTS_W;
    const int wo = (slot % SLOTS_W) * TW;

    const float* xb = x + (size_t)b * CIN * HIN * WIN;

    float acc[TCO][TW];
#pragma unroll
    for (int t = 0; t < TCO; ++t) {
        float bv = bs[cob + t];
#pragma unroll
        for (int j = 0; j < TW; ++j) acc[t][j] = bv;
    }

    const int hi0 = ho * S - PAD;
    const int wi0 = wo * S - PAD;
    constexpr int L = (TW - 1) * S + K;     // input columns needed per row
    const bool interior = (hi0 >= 0) && (hi0 + K <= HIN) && (wi0 >= 0) && (wi0 + L <= WIN);

    for (int ci = 0; ci < CIN; ++ci) {
        const float* xc = xb + (size_t)ci * HIN * WIN;
        const float* wc = &wlds[(ci * K * K) * TCO];
#pragma unroll
        for (int kh = 0; kh < K; ++kh) {
            const int hi = hi0 + kh;
            float r[L];
            if (interior) {
                const float* xr = xc + (size_t)hi * WIN + wi0;
#pragma unroll
                for (int u = 0; u < L; ++u) r[u] = xr[u];
            } else {
                const bool rowok = (unsigned)hi < (unsigned)HIN;
#pragma unroll
                for (int u = 0; u < L; ++u) {
                    const int wi = wi0 + u;
                    r[u] = (rowok && (unsigned)wi < (unsigned)WIN)
                               ? xc[(size_t)hi * WIN + wi] : 0.0f;
                }
            }
#pragma unroll
            for (int kw = 0; kw < K; ++kw) {
                const float* wg = wc + (kh * K + kw) * TCO;
                float w8[TCO];
#pragma unroll
                for (int t = 0; t < TCO; ++t) w8[t] = wg[t];
#pragma unroll
                for (int j = 0; j < TW; ++j) {
                    const float xv = r[kw + j * S];
#pragma unroll
                    for (int t = 0; t < TCO; ++t)
                        acc[t][j] = fmaf(xv, w8[t], acc[t][j]);
                }
            }
        }
    }

    // epilogue: leaky relu + store
#pragma unroll
    for (int t = 0; t < TCO; ++t) {
        float* yr = y + (((size_t)b * COUT + cob + t) * HOUT + ho) * WOUT + wo;
#pragma unroll
        for (int j = 0; j < TW; ++j) {
            const float v = acc[t][j];
            yr[j] = v >= 0.0f ? v : NEG_SLOPE * v;
        }
    }
}

// Compile-time geometry: interior rectangle (no bounds checks needed) vs edge ring.
template <int K, int S, int PAD, int HIN, int WIN, int HOUT, int WOUT, int TW>
struct Geom {
    static constexpr int SLOTS_W = WOUT / TW;       // thread-slots per output row
    static constexpr int NSLOT   = HOUT * SLOTS_W;  // slots per (b, co_group) plane
    static constexpr int L       = (TW - 1) * S + K;
    static constexpr int HO_LO   = (PAD + S - 1) / S;
    static constexpr int HO_HI0  = (HIN - K + PAD) / S + 1;
    static constexpr int HO_HI   = HO_HI0 < HOUT ? HO_HI0 : HOUT;
    static constexpr int WS_LO   = (PAD + TW * S - 1) / (TW * S);
    static constexpr int WS_HI0  = (WIN + PAD - L) / (TW * S) + 1;
    static constexpr int WS_HI   = WS_HI0 < SLOTS_W ? WS_HI0 : SLOTS_W;
    static constexpr int WS_N    = WS_HI - WS_LO;
    static constexpr int N_INT   = (HO_HI - HO_LO) * WS_N;
    static constexpr int N_EDGE  = NSLOT - N_INT;
};

// ---------------- interior conv + leaky relu, L1 only (round-3 EXACT: 144us @ z=16) ----
// Single x pointer; batch count from gridDim.z. Do not touch signature (rule #19).
template <int K, int S, int PAD, int CIN, int COUT,
          int HIN, int WIN, int HOUT, int WOUT, int TCO, int TW>
__global__ __launch_bounds__(256, 4) void conv_int(const float* __restrict__ x,
                                                   const float* __restrict__ w,
                                                   const float* __restrict__ bs,
                                                   float* __restrict__ y) {
    using G = Geom<K, S, PAD, HIN, WIN, HOUT, WOUT, TW>;
    constexpr int NW = TCO * CIN * K * K;

    __shared__ float wlds[NW];

    const int zz  = blockIdx.z;
    const int b   = zz / (COUT / TCO);
    const int cob = (zz % (COUT / TCO)) * TCO;

    for (int i = threadIdx.x; i < NW; i += 256) {
        int t    = i % TCO;
        int rest = i / TCO;
        wlds[i] = w[(size_t)(cob + t) * (CIN * K * K) + rest];
    }
    __syncthreads();

    const int s = blockIdx.x * 256 + threadIdx.x;
    if (s >= G::N_INT) return;

    const int ho = G::HO_LO + s / G::WS_N;
    const int wo = (G::WS_LO + s % G::WS_N) * TW;

    const float* xb = x + (size_t)b * CIN * HIN * WIN;

    float acc[TCO][TW];
#pragma unroll
    for (int t = 0; t < TCO; ++t) {
        float bv = bs[cob + t];
#pragma unroll
        for (int j = 0; j < TW; ++j) acc[t][j] = bv;
    }

    const int hi0 = ho * S - PAD;
    const int wi0 = wo * S - PAD;

#pragma unroll
    for (int ci = 0; ci < CIN; ++ci) {
        const float* xc = xb + (size_t)ci * HIN * WIN;
        const float* wc = &wlds[(ci * K * K) * TCO];
#pragma unroll
        for (int kh = 0; kh < K; ++kh) {
            const float* xr = xc + (size_t)(hi0 + kh) * WIN + wi0;
            float r[G::L];
#pragma unroll
            for (int u = 0; u < G::L; ++u) r[u] = xr[u];
#pragma unroll
            for (int kw = 0; kw < K; ++kw) {
                const float* wg = wc + (kh * K + kw) * TCO;
                float w8[TCO];
                if constexpr ((TCO % 4) == 0) {
#pragma unroll
                    for (int t = 0; t < TCO; t += 4) {
                        float4 q = *reinterpret_cast<const float4*>(wg + t);
                        w8[t] = q.x; w8[t + 1] = q.y; w8[t + 2] = q.z; w8[t + 3] = q.w;
                    }
                } else {
#pragma unroll
                    for (int t = 0; t < TCO; ++t) w8[t] = wg[t];
                }
#pragma unroll
                for (int j = 0; j < TW; ++j) {
                    const float xv = r[kw + j * S];
#pragma unroll
                    for (int t = 0; t < TCO; ++t)
                        acc[t][j] = fmaf(xv, w8[t], acc[t][j]);
                }
            }
        }
    }

#pragma unroll
    for (int t = 0; t < TCO; ++t) {
        float* yr = y + (((size_t)b * COUT + cob + t) * HOUT + ho) * WOUT + wo;
        float v[TW];
#pragma unroll
        for (int j = 0; j < TW; ++j) {
            const float a = acc[t][j];
            v[j] = a >= 0.0f ? a : NEG_SLOPE * a;
        }
        if constexpr (TW == 4) {
            *reinterpret_cast<float4*>(yr) = make_float4(v[0], v[1], v[2], v[3]);
        } else if constexpr (TW == 2) {
            *reinterpret_cast<float2*>(yr) = make_float2(v[0], v[1]);
        } else {
#pragma unroll
            for (int j = 0; j < TW; ++j) yr[j] = v[j];
        }
    }
}

// ---------------- edge conv + leaky relu, L1 only (round-3 EXACT) ----------------
template <int K, int S, int PAD, int CIN, int COUT,
          int HIN, int WIN, int HOUT, int WOUT, int TCO, int TW>
__global__ __launch_bounds__(256) void conv_edge(const float* __restrict__ x,
                                                 const float* __restrict__ w,
                                                 const float* __restrict__ bs,
                                                 float* __restrict__ y) {
    using G = Geom<K, S, PAD, HIN, WIN, HOUT, WOUT, TW>;
    constexpr int SLOTS_W = G::SLOTS_W;
    constexpr int NW = TCO * CIN * K * K;

    __shared__ float wlds[NW];

    const int zz  = blockIdx.z;
    const int b   = zz / (COUT / TCO);
    const int cob = (zz % (COUT / TCO)) * TCO;

    for (int i = threadIdx.x; i < NW; i += 256) {
        int t    = i % TCO;
        int rest = i / TCO;
        wlds[i] = w[(size_t)(cob + t) * (CIN * K * K) + rest];
    }
    __syncthreads();

    const int s = blockIdx.x * 256 + threadIdx.x;
    if (s >= G::N_EDGE) return;

    constexpr int TOPN = G::HO_LO * SLOTS_W;
    constexpr int BOTN = (HOUT - G::HO_HI) * SLOTS_W;
    constexpr int MIDH = G::HO_HI - G::HO_LO;
    constexpr int LW   = G::WS_LO;
    constexpr int RW   = SLOTS_W - G::WS_HI;
    constexpr int LN   = MIDH * LW;

    int ho = 0, ws = 0;
    if (s < TOPN) {
        ho = s / SLOTS_W;
        ws = s % SLOTS_W;
    } else if (s < TOPN + BOTN) {
        int t = s - TOPN;
        ho = G::HO_HI + t / SLOTS_W;
        ws = t % SLOTS_W;
    } else if (s < TOPN + BOTN + LN) {
        int t = s - TOPN - BOTN;
        constexpr int D = LW > 0 ? LW : 1;
        ho = G::HO_LO + t / D;
        ws = t % D;
    } else {
        int t = s - TOPN - BOTN - LN;
        constexpr int D = RW > 0 ? RW : 1;
        ho = G::HO_LO + t / D;
        ws = G::WS_HI + t % D;
    }
    const int wo = ws * TW;

    const float* xb = x + (size_t)b * CIN * HIN * WIN;

    float acc[TCO][TW];
#pragma unroll
    for (int t = 0; t < TCO; ++t) {
        float bv = bs[cob + t];
#pragma unroll
        for (int j = 0; j < TW; ++j) acc[t][j] = bv;
    }

    const int hi0 = ho * S - PAD;
    const int wi0 = wo * S - PAD;

#pragma unroll 2
    for (int ci = 0; ci < CIN; ++ci) {
        const float* xc = xb + (size_t)ci * HIN * WIN;
        const float* wc = &wlds[(ci * K * K) * TCO];
#pragma unroll
        for (int kh = 0; kh < K; ++kh) {
            const int hi = hi0 + kh;
            const bool rowok = (unsigned)hi < (unsigned)HIN;
            const float* xr = xc + (size_t)(rowok ? hi : 0) * WIN;
            float r[G::L];
#pragma unroll
            for (int u = 0; u < G::L; ++u) {
                const int wi = wi0 + u;
                const bool ok = rowok && (unsigned)wi < (unsigned)WIN;
                const float v = xr[ok ? wi : 0];
                r[u] = ok ? v : 0.0f;
            }
#pragma unroll
            for (int kw = 0; kw < K; ++kw) {
                const float* wg = wc + (kh * K + kw) * TCO;
                float w8[TCO];
#pragma unroll
                for (int t = 0; t < TCO; ++t) w8[t] = wg[t];
#pragma unroll
                for (int j = 0; j < TW; ++j) {
                    const float xv = r[kw + j * S];
#pragma unroll
                    for (int t = 0; t < TCO; ++t)
                        acc[t][j] = fmaf(xv, w8[t], acc[t][j]);
                }
            }
        }
    }

#pragma unroll
    for (int t = 0; t < TCO; ++t) {
        float* yr = y + (((size_t)b * COUT + cob + t) * HOUT + ho) * WOUT + wo;
#pragma unroll
        for (int j = 0; j < TW; ++j) {
            const float v = acc[t][j];
            yr[j] = v >= 0.0f ? v : NEG_SLOPE * v;
        }
    }
}

// ---------------- bilinear warp (B=4, H=12, W=24) ----------------
__global__ void warp_kernel(const float* __restrict__ img, const float* __restrict__ flow,
                            float* __restrict__ out, int C) {
    const int H = 12, W = 24, HW = 288;
    int idx = blockIdx.x * blockDim.x + threadIdx.x;
    int total = 4 * C * HW;
    if (idx >= total) return;
    int w = idx % W;
    int h = (idx / W) % H;
    int c = (idx / HW) % C;
    int b = idx / (HW * C);

    float fx = flow[(((size_t)b * 2 + 0) * H + h) * W + w] * 0.625f;
    float fy = flow[(((size_t)b * 2 + 1) * H + h) * W + w] * 0.625f;
    float px = (float)w + fx;
    float py = (float)h + fy;
    float x0f = floorf(px);
    float y0f = floorf(py);
    float wx = px - x0f;
    float wy = py - y0f;
    int x0 = (int)x0f;
    int y0 = (int)y0f;

    const float* ip = img + ((size_t)b * C + c) * HW;
    auto g = [&](int yi, int xi) -> float {
        if (xi < 0 || xi > W - 1 || yi < 0 || yi > H - 1) return 0.0f;
        return ip[yi * W + xi];
    };
    float v = g(y0, x0) * (1.0f - wx) * (1.0f - wy)
            + g(y0, x0 + 1) * wx * (1.0f - wy)
            + g(y0 + 1, x0) * (1.0f - wx) * wy
            + g(y0 + 1, x0 + 1) * wx * wy;
    out[idx] = v;
}

// ---------------- correlation (7x7 disp) + lrelu ----------------
__global__ void corr_lrelu(const float* __restrict__ f1, const float* __restrict__ wp,
                           float* __restrict__ out, int C) {
    const int H = 12, W = 24, HW = 288;
    int idx = blockIdx.x * blockDim.x + threadIdx.x;
    int total = 4 * 49 * HW;
    if (idx >= total) return;
    int w = idx % W;
    int h = (idx / W) % H;
    int d = (idx / HW) % 49;
    int b = idx / (49 * HW);
    int di = d / 7 - 3;
    int dj = d % 7 - 3;
    int h2 = h + di;
    int w2 = w + dj;

    float s = 0.0f;
    if (h2 >= 0 && h2 < H && w2 >= 0 && w2 < W) {
        const float* a = f1 + (size_t)b * C * HW + h * W + w;
        const float* p = wp + (size_t)b * C * HW + h2 * W + w2;
        for (int c = 0; c < C; ++c) s = fmaf(a[(size_t)c * HW], p[(size_t)c * HW], s);
    }
    s /= (float)C;
    s = (s >= 0.0f) ? s : NEG_SLOPE * s;
    out[idx] = s;
}

// ---------------- host ----------------
// Memory plan (fits the proven 191.4 MB workspace; uses 153.6 MB):
//   P   = ws[0          : 18,874,368)   18.9M floats  (half-batch L1 out / tail ping)
//   Q   = ws[18,874,368 : 37,748,736)   18.9M floats  (batch-8 L2 out / tail pong)
//   F12 = ws[37,748,736 : 38,191,104)   442,368       (batch-8 L10 out: b0-3=img1, b4-7=img2)
//   WRP = ws[38,191,104 : 38,412,288)   221,184
// L1/L2 run at half-batch (2 images x 2 halves) so that Q can hold BOTH images' L2
// outputs contiguously; L3..L10 then run once at batch-8 with unchanged conv_blk bodies.
extern "C" void kernel_launch(void* const* d_in, const int* in_sizes, int n_in,
                              void* d_out, int out_size, void* d_ws, size_t ws_size,
                              hipStream_t stream) {
    const float* img1 = (const float*)d_in[0];
    const float* img2 = (const float*)d_in[1];
    const float* flow = (const float*)d_in[2];
    float* out = (float*)d_out;

    const float* W[10];
    const float* Bs[10];
    for (int l = 0; l < 10; ++l) {
        W[l]  = (const float*)d_in[3 + 2 * l];
        Bs[l] = (const float*)d_in[4 + 2 * l];
    }

    float* ws = (float*)d_ws;
    float* P   = ws;
    float* Q   = ws + 18874368;
    float* F12 = ws + 37748736;
    float* WRP = ws + 38191104;

    using G1 = Geom<7,1,3, 384,768, 384,768, 4>;

    // ---- L1+L2 at half-batch (NB=2 => gridDim.z = 2*(32/8) = 8) ----
    const size_t IMG_HALF  = 2ull * 3 * 384 * 768;   // input floats per 2-batch half
    const size_t L2O_HALF  = 2ull * 32 * 192 * 384;  // L2-out floats per 2-batch half

    const float* imgs[2] = { img1, img2 };
    for (int i = 0; i < 2; ++i) {
        for (int h = 0; h < 2; ++h) {
            const float* xin = imgs[i] + (size_t)h * IMG_HALF;
            float* qout = Q + ((size_t)i * 2 + h) * L2O_HALF;
            conv_int<7,1,3,  3, 32, 384,768, 384,768, 8,4>
                <<<dim3(cdiv(G1::N_INT, 256), 1, 2*(32/8)), 256, 0, stream>>>(xin, W[0], Bs[0], P);
            conv_edge<7,1,3,  3, 32, 384,768, 384,768, 8,4>
                <<<dim3(cdiv(G1::N_EDGE, 256), 1, 2*(32/8)), 256, 0, stream>>>(xin, W[0], Bs[0], P);
            conv_blk<3,2,1, 32, 32, 384,768, 192,384, 8,4>
                <<<dim3(cdiv(192*(384/4),256),1,2*(32/8)), 256, 0, stream>>>(P, W[1], Bs[1], qout);
        }
    }

    // ---- L3..L10 at batch-8 (gridDim.z = 8*(COUT/8)); bodies unchanged ----
    conv_blk<3,1,1, 32, 32, 192,384, 192,384, 8,4>
        <<<dim3(cdiv(192*(384/4),256),1,8*(32/8)), 256, 0, stream>>>(Q, W[2], Bs[2], P);
    conv_blk<3,1,1, 32, 32, 192,384, 192,384, 8,4>
        <<<dim3(cdiv(192*(384/4),256),1,8*(32/8)), 256, 0, stream>>>(P, W[3], Bs[3], Q);
    conv_blk<3,2,1, 32, 64, 192,384,  96,192, 8,4>
        <<<dim3(cdiv(96*(192/4),256),1,8*(64/8)), 256, 0, stream>>>(Q, W[4], Bs[4], P);
    conv_blk<3,1,1, 64, 64,  96,192,  96,192, 8,4>
        <<<dim3(cdiv(96*(192/4),256),1,8*(64/8)), 256, 0, stream>>>(P, W[5], Bs[5], Q);
    conv_blk<3,2,1, 64, 96,  96,192,  48, 96, 8,4>
        <<<dim3(cdiv(48*(96/4),256),1,8*(96/8)), 256, 0, stream>>>(Q, W[6], Bs[6], P);
    conv_blk<3,1,1, 96, 96,  48, 96,  48, 96, 8,4>
        <<<dim3(cdiv(48*(96/4),256),1,8*(96/8)), 256, 0, stream>>>(P, W[7], Bs[7], Q);
    conv_blk<3,2,1, 96,128,  48, 96,  24, 48, 8,4>
        <<<dim3(cdiv(24*(48/4),256),1,8*(128/8)), 256, 0, stream>>>(Q, W[8], Bs[8], P);
    conv_blk<3,2,1,128,192,  24, 48,  12, 24, 8,4>
        <<<dim3(cdiv(12*(24/4),256),1,8*(192/8)), 256, 0, stream>>>(P, W[9], Bs[9], F12);

    // ---- warp + correlation ----
    float* f1 = F12;               // batches 0..3  = img1 features
    float* f2 = F12 + 221184;      // batches 4..7  = img2 features
    warp_kernel<<<cdiv(4 * 192 * 288, 256), 256, 0, stream>>>(f2, flow, WRP, 192);
    corr_lrelu<<<cdiv(4 * 49 * 288, 256), 256, 0, stream>>>(f1, WRP, out, 192);
}